// Round 9
// baseline (146.212 us; speedup 1.0000x reference)
//
#include <hip/hip_runtime.h>
#include <hip/hip_cooperative_groups.h>
#include <hip/hip_bf16.h>
#include <math.h>

namespace cg = cooperative_groups;

#define NB 4
#define IW 67
#define HF 63
#define PP 3969
#define PPAD 4096
#define IMGSZ (3*IW*IW)
#define C75 75
#define NSLICE 4
#define CH_PER_SL 8
#define EPSV 1e-5f
#define WSP 0.1f
#define SQ01 0.316227766016838f
#define LOG2E2 2.885390082f      // 2*log2(e)

// ---------------- fast (MFMA) path geometry ----------------
#define KCH 96
#define NKG 12        // KCH/8
#define BM 256
#define BN 128
#define TILES_I 16    // PPAD/BM
#define FEAT_BLOCKS (2*NB*NKG*PPAD/256)   // 1536 (fallback launch)
#define PQ_BLOCKS   (2*NB*PPAD/256)       // 128

typedef __attribute__((ext_vector_type(8))) short short8;
typedef __attribute__((ext_vector_type(4))) float f32x4;

// fast-path workspace float offsets
#define OFF_PI   96                     // NB*PPAD
#define OFF_QJ   (96 + 16384)
#define OFF_DMIN (96 + 2*16384)         // NB*PP used
#define OFF_PART (96 + 3*16384)         // NB*NSLICE*PP = 63504
#define OFF_FPART (96 + 3*16384 + 63504) // 64
#define OFF_CNT   (OFF_FPART + 64)       // 1 (as unsigned)
#define OFF_FB    (OFF_FPART + 80)       // 16B aligned
#define FB_FLOATS (2*NB*NKG*PPAD*4)     // 1572864
#define NEED_BYTES ((size_t)(OFF_FB + FB_FLOATS) * 4)

// old-path offsets
#define OLD_MEAN 0
#define OLD_RI   128
#define OLD_RT   (128 + 15876)
#define OLD_DMIN (128 + 2*15876)
#define OLD_PART (128 + 3*15876)

__device__ __forceinline__ void gload_lds16(const int4* __restrict__ g, int4* l) {
    __builtin_amdgcn_global_load_lds(
        (const __attribute__((address_space(1))) void*)g,
        (__attribute__((address_space(3))) void*)l,
        16, 0, 0);
}

// =====================================================================
// Cooperative single-launch fast path: feat+pq | pass1 | pass2 | fin
// =====================================================================
__global__ __launch_bounds__(512, 2) void k_all(const float* __restrict__ outI,
                                                const float* __restrict__ tgtI,
                                                int4* __restrict__ fb,
                                                float* __restrict__ PiA,
                                                float* __restrict__ QjA,
                                                unsigned* __restrict__ dminU,
                                                float* __restrict__ part,
                                                float* __restrict__ fpart,
                                                unsigned* __restrict__ cnt,
                                                float* __restrict__ out) {
    cg::grid_group grid = cg::this_grid();
    __shared__ __align__(16) int4 lB[2][NKG * BN];
    __shared__ float red[2 * BM];
    __shared__ int lastFlag;

    const int tid = threadIdx.x;
    const int bid = blockIdx.x;

    // ---- Phase A: bf16 feature build (mean cancels in pairwise dists) ----
    for (int idx = bid * 512 + tid; idx < 2 * NB * NKG * PPAD; idx += 256 * 512) {
        int p = idx & (PPAD - 1);
        int t = idx >> 12;
        int kg = t % NKG; int nq = t / NKG;
        int n = nq & (NB - 1); int which = nq >> 2;
        const float* img = (which ? tgtI : outI) + n * IMGSZ;
        int pcl = (p < PP) ? p : (PP - 1);
        int py = pcl / HF, px = pcl - py * HF;
        const float* base = img + py * IW + px;
        unsigned us[8];
        #pragma unroll
        for (int e = 0; e < 8; ++e) {
            int ch = kg * 8 + e;
            float v;
            if (ch < C75) {
                int c = ch / 25, rem = ch - c * 25, ky = rem / 5, kx = rem - ky * 5;
                v = base[(c * IW + ky) * IW + kx];
            } else if (ch == 75) v = SQ01 * (float)py * (1.f / 62.f);
            else if (ch == 76)   v = SQ01 * (float)px * (1.f / 62.f);
            else v = 0.f;
            __hip_bfloat16 h = __float2bfloat16(v);
            us[e] = *reinterpret_cast<unsigned short*>(&h);
        }
        int4 o;
        o.x = (int)(us[0] | (us[1] << 16));
        o.y = (int)(us[2] | (us[3] << 16));
        o.z = (int)(us[4] | (us[5] << 16));
        o.w = (int)(us[6] | (us[7] << 16));
        fb[idx] = o;
    }
    // ---- Phase A2: Pi/Qj + dmin-init + arrive-counter reset ----
    for (int idx = bid * 512 + tid; idx < 2 * NB * PPAD; idx += 256 * 512) {
        if (idx == 0) atomicExch(cnt, 0u);
        int p = idx & (PPAD - 1);
        int nq = idx >> 12; int n = nq & (NB - 1); int which = nq >> 2;
        float* dst = (which ? QjA : PiA) + n * PPAD + p;
        if (p >= PP) { *dst = which ? 1e30f : 0.f; continue; }
        if (!which) dminU[n * PP + p] = 0x7f800000u;
        int py = p / HF, px = p - py * HF;
        float cy = (float)py * (1.f / 62.f), cx = (float)px * (1.f / 62.f);
        float s = WSP * (cy * cy + cx * cx);
        const float* img = (which ? tgtI : outI) + n * IMGSZ + py * IW + px;
        #pragma unroll
        for (int c = 0; c < 3; ++c)
            #pragma unroll
            for (int ky = 0; ky < 5; ++ky)
                #pragma unroll
                for (int kx = 0; kx < 5; ++kx) {
                    float v = img[(c * IW + ky) * IW + kx];
                    s = fmaf(v, v, s);
                }
        *dst = s;
    }
    grid.sync();

    // ---- Common GEMM geometry (BM=256 tile; 8 waves = 4 wr x 2 wc) ----
    const int it = bid & 15, sl = (bid >> 4) & 3, n = bid >> 6;
    const int i0 = it * BM;
    const int wid = tid >> 6, lane = tid & 63;
    const int wr = wid >> 1, wc = wid & 1;
    const int g = lane >> 4, c16 = lane & 15;
    const int seg0 = wid * 3;
    const int4* fbA = fb + (size_t)(n * NKG) * PPAD;
    const int4* fbB = fb + (size_t)((NB + n) * NKG) * PPAD;

    // A fragments global -> registers ONCE, reused by pass1 AND pass2
    short8 af[3][4];
    #pragma unroll
    for (int ks = 0; ks < 3; ++ks)
        #pragma unroll
        for (int mf = 0; mf < 4; ++mf)
            af[ks][mf] = *reinterpret_cast<const short8*>(
                &fbA[(ks * 4 + g) * PPAD + i0 + wr * 64 + mf * 16 + c16]);

    // ================= Phase B: pass 1 (row minima) =================
    {
        float rmin[16];
        #pragma unroll
        for (int q = 0; q < 16; ++q) rmin[q] = 1e30f;

        {
            const int j0 = (sl * CH_PER_SL) * BN;
            #pragma unroll
            for (int s2 = 0; s2 < 3; ++s2) {
                int idx = (seg0 + s2) * 64 + lane;
                int kg = idx >> 7, col = idx & 127;
                gload_lds16(&fbB[kg * PPAD + j0 + col], &lB[0][(seg0 + s2) * 64]);
            }
        }
        __syncthreads();

        int cur = 0;
        for (int ch = 0; ch < CH_PER_SL; ++ch) {
            const int j0 = (sl * CH_PER_SL + ch) * BN;
            if (ch + 1 < CH_PER_SL) {
                const int j1 = j0 + BN;
                #pragma unroll
                for (int s2 = 0; s2 < 3; ++s2) {
                    int idx = (seg0 + s2) * 64 + lane;
                    int kg = idx >> 7, col = idx & 127;
                    gload_lds16(&fbB[kg * PPAD + j1 + col], &lB[cur ^ 1][(seg0 + s2) * 64]);
                }
            }
            float qj[4];
            #pragma unroll
            for (int nf = 0; nf < 4; ++nf)
                qj[nf] = QjA[n * PPAD + j0 + wc * 64 + nf * 16 + c16];

            f32x4 acc[4][4];
            #pragma unroll
            for (int mf = 0; mf < 4; ++mf)
                #pragma unroll
                for (int nf = 0; nf < 4; ++nf)
                    acc[mf][nf] = (f32x4)(0.f);

            #pragma unroll
            for (int ks = 0; ks < 3; ++ks) {
                short8 bfr[4];
                #pragma unroll
                for (int nf = 0; nf < 4; ++nf)
                    bfr[nf] = *reinterpret_cast<const short8*>(
                        &lB[cur][(ks * 4 + g) * BN + wc * 64 + nf * 16 + c16]);
                #pragma unroll
                for (int mf = 0; mf < 4; ++mf)
                    #pragma unroll
                    for (int nf = 0; nf < 4; ++nf)
                        acc[mf][nf] = __builtin_amdgcn_mfma_f32_16x16x32_bf16(af[ks][mf], bfr[nf], acc[mf][nf], 0, 0, 0);
            }

            #pragma unroll
            for (int nf = 0; nf < 4; ++nf)
                #pragma unroll
                for (int mf = 0; mf < 4; ++mf)
                    #pragma unroll
                    for (int r = 0; r < 4; ++r) {
                        int q = mf * 4 + r;
                        rmin[q] = fminf(rmin[q], fmaf(-2.f, acc[mf][nf][r], qj[nf]));
                    }
            __syncthreads();
            cur ^= 1;
        }

        #pragma unroll
        for (int q = 0; q < 16; ++q) {
            float v = rmin[q];
            #pragma unroll
            for (int m = 1; m <= 8; m <<= 1) v = fminf(v, __shfl_xor(v, m));
            if (c16 == 0) {
                int mf = q >> 2, r = q & 3;
                red[wc * BM + wr * 64 + mf * 16 + g * 4 + r] = v;
            }
        }
        __syncthreads();
        if (tid < BM) {
            int i = i0 + tid;
            if (i < PP) {
                float v = fminf(red[tid], red[BM + tid]) + PiA[n * PPAD + i];
                atomicMin(dminU + n * PP + i, __float_as_uint(v));
            }
        }
    }
    grid.sync();

    // ================= Phase C: pass 2 (exp sums) =================
    {
        float racc[16], slope[16], c0[16];
        #pragma unroll
        for (int mf = 0; mf < 4; ++mf)
            #pragma unroll
            for (int r = 0; r < 4; ++r) {
                int q = mf * 4 + r;
                racc[q] = 0.f;
                int i = i0 + wr * 64 + mf * 16 + g * 4 + r;
                int ic = (i < PP) ? i : (PP - 1);
                float u = LOG2E2 / (__uint_as_float(dminU[n * PP + ic]) + EPSV);
                slope[q] = 2.f * u;
                c0[q] = fmaf(-u, PiA[n * PPAD + i], LOG2E2);
            }

        {
            const int j0 = (sl * CH_PER_SL) * BN;
            #pragma unroll
            for (int s2 = 0; s2 < 3; ++s2) {
                int idx = (seg0 + s2) * 64 + lane;
                int kg = idx >> 7, col = idx & 127;
                gload_lds16(&fbB[kg * PPAD + j0 + col], &lB[0][(seg0 + s2) * 64]);
            }
        }
        __syncthreads();

        int cur = 0;
        for (int ch = 0; ch < CH_PER_SL; ++ch) {
            const int j0 = (sl * CH_PER_SL + ch) * BN;
            if (ch + 1 < CH_PER_SL) {
                const int j1 = j0 + BN;
                #pragma unroll
                for (int s2 = 0; s2 < 3; ++s2) {
                    int idx = (seg0 + s2) * 64 + lane;
                    int kg = idx >> 7, col = idx & 127;
                    gload_lds16(&fbB[kg * PPAD + j1 + col], &lB[cur ^ 1][(seg0 + s2) * 64]);
                }
            }
            float qj[4];
            #pragma unroll
            for (int nf = 0; nf < 4; ++nf)
                qj[nf] = QjA[n * PPAD + j0 + wc * 64 + nf * 16 + c16];

            f32x4 acc[4][4];
            #pragma unroll
            for (int mf = 0; mf < 4; ++mf)
                #pragma unroll
                for (int nf = 0; nf < 4; ++nf)
                    acc[mf][nf] = (f32x4)(0.f);

            #pragma unroll
            for (int ks = 0; ks < 3; ++ks) {
                short8 bfr[4];
                #pragma unroll
                for (int nf = 0; nf < 4; ++nf)
                    bfr[nf] = *reinterpret_cast<const short8*>(
                        &lB[cur][(ks * 4 + g) * BN + wc * 64 + nf * 16 + c16]);
                #pragma unroll
                for (int mf = 0; mf < 4; ++mf)
                    #pragma unroll
                    for (int nf = 0; nf < 4; ++nf)
                        acc[mf][nf] = __builtin_amdgcn_mfma_f32_16x16x32_bf16(af[ks][mf], bfr[nf], acc[mf][nf], 0, 0, 0);
            }

            #pragma unroll
            for (int nf = 0; nf < 4; ++nf) {
                float qjh = -0.5f * qj[nf];
                float bq[16];
                #pragma unroll
                for (int q = 0; q < 16; ++q)
                    bq[q] = fmaf(slope[q], qjh, c0[q]);
                #pragma unroll
                for (int mf = 0; mf < 4; ++mf)
                    #pragma unroll
                    for (int r = 0; r < 4; ++r) {
                        int q = mf * 4 + r;
                        racc[q] += __builtin_amdgcn_exp2f(fmaf(slope[q], acc[mf][nf][r], bq[q]));
                    }
            }
            __syncthreads();
            cur ^= 1;
        }

        #pragma unroll
        for (int q = 0; q < 16; ++q) {
            float v = racc[q];
            #pragma unroll
            for (int m = 1; m <= 8; m <<= 1) v += __shfl_xor(v, m);
            if (c16 == 0) {
                int mf = q >> 2, r = q & 3;
                red[wc * BM + wr * 64 + mf * 16 + g * 4 + r] = v;
            }
        }
        __syncthreads();
        if (tid < BM) {
            int i = i0 + tid;
            if (i < PP)
                part[(n * NSLICE + sl) * PP + i] = red[tid] + red[BM + tid];
        }
    }
    grid.sync();

    // ================= Phase D: finish (32 blocks, 512 thr) ==========
    if (bid < 32) {
        int nD = bid >> 3, cD = bid & 7;
        int i = cD * 512 + tid;
        float v = 0.f;
        if (i < PP) {
            float dm = __uint_as_float(dminU[nD * PP + i]);
            float inv = 1.f / (dm + EPSV);
            float num = __expf(2.f * (1.f - dm * inv));
            float S = part[(nD * NSLICE + 0) * PP + i] + part[(nD * NSLICE + 1) * PP + i]
                    + part[(nD * NSLICE + 2) * PP + i] + part[(nD * NSLICE + 3) * PP + i];
            v = num / S;
        }
        red[tid] = v; __syncthreads();
        for (int w = 256; w > 0; w >>= 1) { if (tid < w) red[tid] += red[tid + w]; __syncthreads(); }
        if (tid == 0) {
            atomicExch(&fpart[bid], red[0]);
            __threadfence();
            unsigned old = atomicAdd(cnt, 1u);
            lastFlag = (old == 31u);
        }
        __syncthreads();
        if (lastFlag && tid < 64) {
            __threadfence();
            float s = (tid < 32) ? atomicAdd(&fpart[tid], 0.f) : 0.f;
            s += __shfl_xor(s, 1);
            s += __shfl_xor(s, 2);
            s += __shfl_xor(s, 4);
            float s0 = __shfl(s, 0);
            float s1 = __shfl(s, 8);
            float s2 = __shfl(s, 16);
            float s3 = __shfl(s, 24);
            if (tid == 0) {
                const float invP = 1.f / (float)PP;
                out[0] = -(__logf(s0 * invP) + __logf(s1 * invP)
                         + __logf(s2 * invP) + __logf(s3 * invP));
            }
        }
    }
}

// =====================================================================
// Round-8 4-kernel fast path (fallback if cooperative launch errors)
// =====================================================================
__global__ __launch_bounds__(256) void k_featpq(const float* __restrict__ outI,
                                                const float* __restrict__ tgtI,
                                                int4* __restrict__ fb,
                                                float* __restrict__ PiA,
                                                float* __restrict__ QjA,
                                                unsigned* __restrict__ dminU,
                                                unsigned* __restrict__ cnt) {
    int b = blockIdx.x;
    int tid = threadIdx.x;
    if (b < FEAT_BLOCKS) {
        int idx = b * 256 + tid;
        int p = idx & (PPAD - 1);
        int t = idx >> 12;
        int kg = t % NKG; int nq = t / NKG;
        int n = nq & (NB - 1); int which = nq >> 2;
        const float* img = (which ? tgtI : outI) + n * IMGSZ;
        int pcl = (p < PP) ? p : (PP - 1);
        int py = pcl / HF, px = pcl - py * HF;
        const float* base = img + py * IW + px;
        unsigned us[8];
        #pragma unroll
        for (int e = 0; e < 8; ++e) {
            int ch = kg * 8 + e;
            float v;
            if (ch < C75) {
                int c = ch / 25, rem = ch - c * 25, ky = rem / 5, kx = rem - ky * 5;
                v = base[(c * IW + ky) * IW + kx];
            } else if (ch == 75) v = SQ01 * (float)py * (1.f / 62.f);
            else if (ch == 76)   v = SQ01 * (float)px * (1.f / 62.f);
            else v = 0.f;
            __hip_bfloat16 h = __float2bfloat16(v);
            us[e] = *reinterpret_cast<unsigned short*>(&h);
        }
        int4 o;
        o.x = (int)(us[0] | (us[1] << 16));
        o.y = (int)(us[2] | (us[3] << 16));
        o.z = (int)(us[4] | (us[5] << 16));
        o.w = (int)(us[6] | (us[7] << 16));
        fb[idx] = o;
    } else {
        int idx = (b - FEAT_BLOCKS) * 256 + tid;
        if (idx == 0) atomicExch(cnt, 0u);
        int p = idx & (PPAD - 1);
        int nq = idx >> 12; int n = nq & (NB - 1); int which = nq >> 2;
        float* dst = (which ? QjA : PiA) + n * PPAD + p;
        if (p >= PP) { *dst = which ? 1e30f : 0.f; return; }
        if (!which) dminU[n * PP + p] = 0x7f800000u;
        int py = p / HF, px = p - py * HF;
        float cy = (float)py * (1.f / 62.f), cx = (float)px * (1.f / 62.f);
        float s = WSP * (cy * cy + cx * cx);
        const float* img = (which ? tgtI : outI) + n * IMGSZ + py * IW + px;
        #pragma unroll
        for (int c = 0; c < 3; ++c)
            #pragma unroll
            for (int ky = 0; ky < 5; ++ky)
                #pragma unroll
                for (int kx = 0; kx < 5; ++kx) {
                    float v = img[(c * IW + ky) * IW + kx];
                    s = fmaf(v, v, s);
                }
        *dst = s;
    }
}

template<int PASS>
__global__ __launch_bounds__(512, 2) void k_pass(const int4* __restrict__ fb,
                                                 const float* __restrict__ PiA,
                                                 const float* __restrict__ QjA,
                                                 unsigned* __restrict__ dminU,
                                                 float* __restrict__ part) {
    __shared__ __align__(16) int4 lB[2][NKG * BN];
    __shared__ float red[2 * BM];

    const int tid = threadIdx.x;
    const int it = blockIdx.x, sl = blockIdx.y, n = blockIdx.z;
    const int i0 = it * BM;
    const int wid = tid >> 6, lane = tid & 63;
    const int wr = wid >> 1, wc = wid & 1;
    const int g = lane >> 4, c16 = lane & 15;

    const int4* fbA = fb + (size_t)(n * NKG) * PPAD;
    const int4* fbB = fb + (size_t)((NB + n) * NKG) * PPAD;

    short8 af[3][4];
    #pragma unroll
    for (int ks = 0; ks < 3; ++ks)
        #pragma unroll
        for (int mf = 0; mf < 4; ++mf)
            af[ks][mf] = *reinterpret_cast<const short8*>(
                &fbA[(ks * 4 + g) * PPAD + i0 + wr * 64 + mf * 16 + c16]);

    float rmin[16], racc[16], slope[16], c0[16];
    #pragma unroll
    for (int mf = 0; mf < 4; ++mf)
        #pragma unroll
        for (int r = 0; r < 4; ++r) {
            int q = mf * 4 + r;
            rmin[q] = 1e30f; racc[q] = 0.f;
            if (PASS == 2) {
                int i = i0 + wr * 64 + mf * 16 + g * 4 + r;
                int ic = (i < PP) ? i : (PP - 1);
                float u = LOG2E2 / (__uint_as_float(dminU[n * PP + ic]) + EPSV);
                slope[q] = 2.f * u;
                c0[q] = fmaf(-u, PiA[n * PPAD + i], LOG2E2);
            }
        }

    const int seg0 = wid * 3;
    {
        const int j0 = (sl * CH_PER_SL) * BN;
        #pragma unroll
        for (int s2 = 0; s2 < 3; ++s2) {
            int idx = (seg0 + s2) * 64 + lane;
            int kg = idx >> 7, col = idx & 127;
            gload_lds16(&fbB[kg * PPAD + j0 + col], &lB[0][(seg0 + s2) * 64]);
        }
    }
    __syncthreads();

    int cur = 0;
    for (int ch = 0; ch < CH_PER_SL; ++ch) {
        const int j0 = (sl * CH_PER_SL + ch) * BN;
        if (ch + 1 < CH_PER_SL) {
            const int j1 = j0 + BN;
            #pragma unroll
            for (int s2 = 0; s2 < 3; ++s2) {
                int idx = (seg0 + s2) * 64 + lane;
                int kg = idx >> 7, col = idx & 127;
                gload_lds16(&fbB[kg * PPAD + j1 + col], &lB[cur ^ 1][(seg0 + s2) * 64]);
            }
        }
        float qj[4];
        #pragma unroll
        for (int nf = 0; nf < 4; ++nf)
            qj[nf] = QjA[n * PPAD + j0 + wc * 64 + nf * 16 + c16];

        f32x4 acc[4][4];
        #pragma unroll
        for (int mf = 0; mf < 4; ++mf)
            #pragma unroll
            for (int nf = 0; nf < 4; ++nf)
                acc[mf][nf] = (f32x4)(0.f);

        #pragma unroll
        for (int ks = 0; ks < 3; ++ks) {
            short8 bfr[4];
            #pragma unroll
            for (int nf = 0; nf < 4; ++nf)
                bfr[nf] = *reinterpret_cast<const short8*>(
                    &lB[cur][(ks * 4 + g) * BN + wc * 64 + nf * 16 + c16]);
            #pragma unroll
            for (int mf = 0; mf < 4; ++mf)
                #pragma unroll
                for (int nf = 0; nf < 4; ++nf)
                    acc[mf][nf] = __builtin_amdgcn_mfma_f32_16x16x32_bf16(af[ks][mf], bfr[nf], acc[mf][nf], 0, 0, 0);
        }

        if (PASS == 1) {
            #pragma unroll
            for (int nf = 0; nf < 4; ++nf)
                #pragma unroll
                for (int mf = 0; mf < 4; ++mf)
                    #pragma unroll
                    for (int r = 0; r < 4; ++r) {
                        int q = mf * 4 + r;
                        rmin[q] = fminf(rmin[q], fmaf(-2.f, acc[mf][nf][r], qj[nf]));
                    }
        } else {
            #pragma unroll
            for (int nf = 0; nf < 4; ++nf) {
                float qjh = -0.5f * qj[nf];
                float bq[16];
                #pragma unroll
                for (int q = 0; q < 16; ++q)
                    bq[q] = fmaf(slope[q], qjh, c0[q]);
                #pragma unroll
                for (int mf = 0; mf < 4; ++mf)
                    #pragma unroll
                    for (int r = 0; r < 4; ++r) {
                        int q = mf * 4 + r;
                        racc[q] += __builtin_amdgcn_exp2f(fmaf(slope[q], acc[mf][nf][r], bq[q]));
                    }
            }
        }
        __syncthreads();
        cur ^= 1;
    }

    #pragma unroll
    for (int q = 0; q < 16; ++q) {
        float v = (PASS == 1) ? rmin[q] : racc[q];
        #pragma unroll
        for (int m = 1; m <= 8; m <<= 1) {
            float o = __shfl_xor(v, m);
            v = (PASS == 1) ? fminf(v, o) : (v + o);
        }
        if (c16 == 0) {
            int mf = q >> 2, r = q & 3;
            red[wc * BM + wr * 64 + mf * 16 + g * 4 + r] = v;
        }
    }
    __syncthreads();
    if (tid < BM) {
        int i = i0 + tid;
        if (i < PP) {
            if (PASS == 1) {
                float v = fminf(red[tid], red[BM + tid]) + PiA[n * PPAD + i];
                atomicMin(dminU + n * PP + i, __float_as_uint(v));
            } else {
                part[(n * NSLICE + sl) * PP + i] = red[tid] + red[BM + tid];
            }
        }
    }
}

__global__ __launch_bounds__(256) void k_fin(const unsigned* __restrict__ dminU,
                                             const float* __restrict__ part,
                                             float* __restrict__ fpart,
                                             unsigned* __restrict__ cnt,
                                             float* __restrict__ out) {
    __shared__ float red[256];
    __shared__ int lastFlag;
    int b = blockIdx.x;           // 64
    int n = b >> 4, c = b & 15;
    int tid = threadIdx.x;
    int i = c * 256 + tid;
    float v = 0.f;
    if (i < PP) {
        float dm = __uint_as_float(dminU[n * PP + i]);
        float inv = 1.f / (dm + EPSV);
        float num = __expf(2.f * (1.f - dm * inv));
        float S = part[(n * NSLICE + 0) * PP + i] + part[(n * NSLICE + 1) * PP + i]
                + part[(n * NSLICE + 2) * PP + i] + part[(n * NSLICE + 3) * PP + i];
        v = num / S;
    }
    red[tid] = v; __syncthreads();
    for (int w = 128; w > 0; w >>= 1) { if (tid < w) red[tid] += red[tid + w]; __syncthreads(); }
    if (tid == 0) {
        atomicExch(&fpart[b], red[0]);
        __threadfence();
        unsigned old = atomicAdd(cnt, 1u);
        lastFlag = (old == 63u);
    }
    __syncthreads();
    if (lastFlag && tid < 64) {
        __threadfence();
        float s = atomicAdd(&fpart[tid], 0.f);
        s += __shfl_xor(s, 1);
        s += __shfl_xor(s, 2);
        s += __shfl_xor(s, 4);
        s += __shfl_xor(s, 8);
        float s0 = __shfl(s, 0);
        float s1 = __shfl(s, 16);
        float s2 = __shfl(s, 32);
        float s3 = __shfl(s, 48);
        if (tid == 0) {
            const float invP = 1.f / (float)PP;
            out[0] = -(__logf(s0 * invP) + __logf(s1 * invP)
                     + __logf(s2 * invP) + __logf(s3 * invP));
        }
    }
}

// ---------------- fallback f32 path (round-1, verified; centered) ---------
__global__ void k_init(unsigned* __restrict__ dminU) {
    int g = blockIdx.x * 256 + threadIdx.x;
    if (g < NB * PP) dminU[g] = 0x7f800000u;
}

__global__ __launch_bounds__(256) void k_mean(const float* __restrict__ tgt,
                                              float* __restrict__ meanv) {
    __shared__ float red[256];
    int c75 = blockIdx.x;
    int c = c75 / 25, rem = c75 - c * 25, ky = rem / 5, kx = rem - ky * 5;
    int tid = threadIdx.x;
    float s = 0.f;
    for (int idx = tid; idx < NB * PP; idx += 256) {
        int n = idx / PP, p = idx - n * PP;
        int py = p / HF, px = p - py * HF;
        s += tgt[n * IMGSZ + (c * IW + py + ky) * IW + px + kx];
    }
    red[tid] = s; __syncthreads();
    for (int w = 128; w > 0; w >>= 1) { if (tid < w) red[tid] += red[tid + w]; __syncthreads(); }
    if (tid == 0) meanv[c75] = red[0] * (1.f / (float)(NB * PP));
}

__global__ __launch_bounds__(256) void k_rsqF(const float* __restrict__ outI,
                                              const float* __restrict__ tgtI,
                                              const float* __restrict__ meanv,
                                              float* __restrict__ rI, float* __restrict__ rT) {
    int gidx = blockIdx.x * 256 + threadIdx.x;
    if (gidx >= 2 * NB * PP) return;
    int which = gidx / (NB * PP); int rem = gidx - which * NB * PP;
    int n = rem / PP, p = rem - n * PP;
    int py = p / HF, px = p - py * HF;
    const float* img = (which ? tgtI : outI) + n * IMGSZ;
    float s = 0.f;
    #pragma unroll
    for (int c = 0; c < 3; ++c)
        #pragma unroll
        for (int ky = 0; ky < 5; ++ky)
            #pragma unroll
            for (int kx = 0; kx < 5; ++kx) {
                float v = img[(c * IW + py + ky) * IW + px + kx] - meanv[(c * 5 + ky) * 5 + kx];
                s = fmaf(v, v, s);
            }
    (which ? rT : rI)[n * PP + p] = s;
}

__device__ __forceinline__ void stage_featF(const float* __restrict__ img,
                                            const float* __restrict__ meanv,
                                            float* __restrict__ lds, int p0, int tid) {
    for (int idx = tid; idx < C75 * 128; idx += 256) {
        int c75 = idx >> 7, col = idx & 127;
        int p = p0 + col; p = (p < PP) ? p : (PP - 1);
        int py = p / HF, px = p - py * HF;
        int c = c75 / 25, rem = c75 - c * 25, ky = rem / 5, kx = rem - ky * 5;
        lds[idx] = img[(c * IW + py + ky) * IW + px + kx] - meanv[c75];
    }
}

template<int PASS>
__global__ __launch_bounds__(256, 2) void k_passF(const float* __restrict__ outI,
                                                  const float* __restrict__ tgtI,
                                                  const float* __restrict__ meanv,
                                                  const float* __restrict__ rI,
                                                  const float* __restrict__ rT,
                                                  unsigned* __restrict__ dminU,
                                                  float* __restrict__ part) {
    __shared__ __align__(16) float lA[C75 * 128];
    __shared__ __align__(16) float lB[C75 * 128];
    __shared__ float red[4 * 128];
    __shared__ float lrT[128];

    const int tid = threadIdx.x;
    const int it = blockIdx.x, sl = blockIdx.y, n = blockIdx.z;
    const int i0 = it * 128;
    const int ti4 = (tid & 15) * 4;
    const int tj4 = (tid >> 4) * 4;

    stage_featF(outI + n * IMGSZ, meanv, lA, i0, tid);

    int lr[8]; float iyn[8], ixn[8], rIr[8], invr[8];
    #pragma unroll
    for (int r = 0; r < 8; ++r) {
        lr[r] = (r < 4) ? (ti4 + r) : (64 + ti4 + (r - 4));
        int i = i0 + lr[r]; int ic = (i < PP) ? i : (PP - 1);
        int iy = ic / HF, ix = ic - iy * HF;
        iyn[r] = (float)iy / 62.f; ixn[r] = (float)ix / 62.f;
        rIr[r] = rI[n * PP + ic];
        if (PASS == 2) {
            float dm = __uint_as_float(dminU[n * PP + ic]);
            invr[r] = 1.f / (dm + EPSV);
        }
    }

    float raccF[8];
    #pragma unroll
    for (int r = 0; r < 8; ++r) raccF[r] = (PASS == 1) ? 3.0e38f : 0.f;

    for (int ch = 0; ch < CH_PER_SL; ++ch) {
        const int j0 = (sl * CH_PER_SL + ch) * 128;
        __syncthreads();
        stage_featF(tgtI + n * IMGSZ, meanv, lB, j0, tid);
        if (tid < 128) {
            int j = j0 + tid;
            lrT[tid] = rT[n * PP + ((j < PP) ? j : (PP - 1))];
        }
        __syncthreads();

        float jyn[8], jxn[8], rTr[8]; bool jok[8];
        #pragma unroll
        for (int s = 0; s < 8; ++s) {
            int jc = (s < 4) ? (tj4 + s) : (64 + tj4 + (s - 4));
            int j = j0 + jc;
            jok[s] = (j < PP);
            int jcl = jok[s] ? j : (PP - 1);
            int jy = jcl / HF, jx = jcl - jy * HF;
            jyn[s] = (float)jy / 62.f; jxn[s] = (float)jx / 62.f;
            rTr[s] = lrT[jc];
        }

        float acc[8][8];
        #pragma unroll
        for (int r = 0; r < 8; ++r)
            #pragma unroll
            for (int s = 0; s < 8; ++s) acc[r][s] = 0.f;

        #pragma unroll 3
        for (int c = 0; c < C75; ++c) {
            const float4 a0 = *reinterpret_cast<const float4*>(lA + c * 128 + ti4);
            const float4 a1 = *reinterpret_cast<const float4*>(lA + c * 128 + 64 + ti4);
            const float4 b0 = *reinterpret_cast<const float4*>(lB + c * 128 + tj4);
            const float4 b1 = *reinterpret_cast<const float4*>(lB + c * 128 + 64 + tj4);
            const float av[8] = {a0.x, a0.y, a0.z, a0.w, a1.x, a1.y, a1.z, a1.w};
            const float bv[8] = {b0.x, b0.y, b0.z, b0.w, b1.x, b1.y, b1.z, b1.w};
            #pragma unroll
            for (int r = 0; r < 8; ++r)
                #pragma unroll
                for (int s = 0; s < 8; ++s)
                    acc[r][s] = fmaf(av[r], bv[s], acc[r][s]);
        }

        #pragma unroll
        for (int r = 0; r < 8; ++r) {
            #pragma unroll
            for (int s = 0; s < 8; ++s) {
                float d = rIr[r] + rTr[s] - 2.f * acc[r][s];
                d = fmaxf(d, 0.f);
                float dy = iyn[r] - jyn[s], dx = ixn[r] - jxn[s];
                float comb = d + WSP * (dy * dy + dx * dx);
                if (PASS == 1) {
                    raccF[r] = fminf(raccF[r], jok[s] ? comb : 3.0e38f);
                } else {
                    float w = __expf(2.f * (1.f - comb * invr[r]));
                    raccF[r] += jok[s] ? w : 0.f;
                }
            }
        }
    }

    const int wv = tid >> 6;
    const bool wrt = ((tid >> 4) & 3) == 0;
    #pragma unroll
    for (int r = 0; r < 8; ++r) {
        float v = raccF[r];
        if (PASS == 1) {
            v = fminf(v, __shfl_xor(v, 16));
            v = fminf(v, __shfl_xor(v, 32));
        } else {
            v += __shfl_xor(v, 16);
            v += __shfl_xor(v, 32);
        }
        if (wrt) red[wv * 128 + lr[r]] = v;
    }
    __syncthreads();
    if (tid < 128) {
        int i = i0 + tid;
        if (i < PP) {
            if (PASS == 1) {
                float v = fminf(fminf(red[tid], red[128 + tid]),
                                fminf(red[256 + tid], red[384 + tid]));
                atomicMin(dminU + n * PP + i, __float_as_uint(v));
            } else {
                float v = red[tid] + red[128 + tid] + red[256 + tid] + red[384 + tid];
                part[(n * NSLICE + sl) * PP + i] = v;
            }
        }
    }
}

__global__ __launch_bounds__(256) void k_finF(const unsigned* __restrict__ dminU,
                                              const float* __restrict__ part,
                                              float* __restrict__ out) {
    __shared__ float red[256];
    int tid = threadIdx.x;
    float loss = 0.f;
    for (int n = 0; n < NB; ++n) {
        float local = 0.f;
        for (int i = tid; i < PP; i += 256) {
            float dm = __uint_as_float(dminU[n * PP + i]);
            float inv = 1.f / (dm + EPSV);
            float num = __expf(2.f * (1.f - dm * inv));
            float S = part[(n * NSLICE + 0) * PP + i] + part[(n * NSLICE + 1) * PP + i]
                    + part[(n * NSLICE + 2) * PP + i] + part[(n * NSLICE + 3) * PP + i];
            local += num / S;
        }
        red[tid] = local; __syncthreads();
        for (int w = 128; w > 0; w >>= 1) { if (tid < w) red[tid] += red[tid + w]; __syncthreads(); }
        if (tid == 0) loss -= __logf(red[0] * (1.f / (float)PP));
        __syncthreads();
    }
    if (tid == 0) out[0] = loss;
}

// ---------------- launcher ----------------
extern "C" void kernel_launch(void* const* d_in, const int* in_sizes, int n_in,
                              void* d_out, int out_size, void* d_ws, size_t ws_size,
                              hipStream_t stream) {
    const float* outI = (const float*)d_in[0];
    const float* tgtI = (const float*)d_in[1];
    float* ws = (float*)d_ws;
    float* outp = (float*)d_out;

    if (ws_size >= NEED_BYTES) {
        float* PiA = ws + OFF_PI;
        float* QjA = ws + OFF_QJ;
        unsigned* dminU = (unsigned*)(ws + OFF_DMIN);
        float* part = ws + OFF_PART;
        float* fpart = ws + OFF_FPART;
        unsigned* cnt = (unsigned*)(ws + OFF_CNT);
        int4* fb = (int4*)(ws + OFF_FB);

        void* args[] = { (void*)&outI, (void*)&tgtI, (void*)&fb, (void*)&PiA,
                         (void*)&QjA, (void*)&dminU, (void*)&part, (void*)&fpart,
                         (void*)&cnt, (void*)&outp };
        hipError_t e = hipLaunchCooperativeKernel((const void*)k_all, dim3(256), dim3(512),
                                                  args, 0, stream);
        if (e != hipSuccess) {
            // fallback: verified round-8 4-kernel sequence
            k_featpq<<<FEAT_BLOCKS + PQ_BLOCKS, 256, 0, stream>>>(outI, tgtI, fb, PiA, QjA, dminU, cnt);
            dim3 g(TILES_I, NSLICE, NB);
            k_pass<1><<<g, 512, 0, stream>>>(fb, PiA, QjA, dminU, part);
            k_pass<2><<<g, 512, 0, stream>>>(fb, PiA, QjA, dminU, part);
            k_fin<<<64, 256, 0, stream>>>(dminU, part, fpart, cnt, outp);
        }
    } else {
        float* meanv = ws + OLD_MEAN;
        float* rI = ws + OLD_RI;
        float* rT = ws + OLD_RT;
        unsigned* dminU = (unsigned*)(ws + OLD_DMIN);
        float* part = ws + OLD_PART;

        k_init<<<(NB * PP + 255) / 256, 256, 0, stream>>>(dminU);
        k_mean<<<C75, 256, 0, stream>>>(tgtI, meanv);
        k_rsqF<<<(2 * NB * PP + 255) / 256, 256, 0, stream>>>(outI, tgtI, meanv, rI, rT);
        dim3 g(32, NSLICE, NB);
        k_passF<1><<<g, 256, 0, stream>>>(outI, tgtI, meanv, rI, rT, dminU, part);
        k_passF<2><<<g, 256, 0, stream>>>(outI, tgtI, meanv, rI, rT, dminU, part);
        k_finF<<<1, 256, 0, stream>>>(dminU, part, outp);
    }
}

// Round 10
// 49.184 us; speedup vs baseline: 2.9727x; 2.9727x over previous
//
#include <hip/hip_runtime.h>
#include <hip/hip_bf16.h>
#include <math.h>

#define NB 4
#define IW 67
#define HF 63
#define PP 3969
#define PPAD 4096
#define IMGSZ (3*IW*IW)
#define C75 75
#define NSLICE 4
#define CH_PER_SL 8
#define EPSV 1e-5f
#define WSP 0.1f
#define SQ01 0.316227766016838f
#define LOG2E2 2.885390082f      // 2*log2(e)

// ---------------- fast (MFMA) path geometry ----------------
#define KCH 96
#define NKG 12        // KCH/8
#define BM 256
#define BN 128
#define TILES_I 16    // PPAD/BM
#define FEAT_BLOCKS (2*NB*NKG*PPAD/256)   // 1536
#define PQ_BLOCKS   (2*NB*PPAD/256)       // 128

typedef __attribute__((ext_vector_type(8))) short short8;
typedef __attribute__((ext_vector_type(4))) float f32x4;

// fast-path workspace float offsets
#define OFF_PI   96                     // NB*PPAD
#define OFF_QJ   (96 + 16384)
#define OFF_DMIN (96 + 2*16384)         // NB*PP used
#define OFF_PART (96 + 3*16384)         // NB*NSLICE*PP = 63504
#define OFF_FPART (96 + 3*16384 + 63504) // 64
#define OFF_CNT   (OFF_FPART + 64)       // 1 (as unsigned)
#define OFF_FB    (OFF_FPART + 80)       // 16B aligned
#define FB_FLOATS (2*NB*NKG*PPAD*4)     // 1572864
#define NEED_BYTES ((size_t)(OFF_FB + FB_FLOATS) * 4)

// old-path offsets
#define OLD_MEAN 0
#define OLD_RI   128
#define OLD_RT   (128 + 15876)
#define OLD_DMIN (128 + 2*15876)
#define OLD_PART (128 + 3*15876)

__device__ __forceinline__ void gload_lds16(const int4* __restrict__ g, int4* l) {
    __builtin_amdgcn_global_load_lds(
        (const __attribute__((address_space(1))) void*)g,
        (__attribute__((address_space(3))) void*)l,
        16, 0, 0);
}

// ---------------- fast path: fused feat + pq + dmin-init + cnt-reset ------
// Mean centering cancels in pairwise distances (I_i - T_j is mean-free), so
// features are RAW pixels + sqrt(0.1)-scaled coords. No mean kernel needed.
__global__ __launch_bounds__(256) void k_featpq(const float* __restrict__ outI,
                                                const float* __restrict__ tgtI,
                                                int4* __restrict__ fb,
                                                float* __restrict__ PiA,
                                                float* __restrict__ QjA,
                                                unsigned* __restrict__ dminU,
                                                unsigned* __restrict__ cnt) {
    int b = blockIdx.x;
    int tid = threadIdx.x;
    if (b < FEAT_BLOCKS) {
        int idx = b * 256 + tid;
        int p = idx & (PPAD - 1);
        int t = idx >> 12;
        int kg = t % NKG; int nq = t / NKG;
        int n = nq & (NB - 1); int which = nq >> 2;
        const float* img = (which ? tgtI : outI) + n * IMGSZ;
        int pcl = (p < PP) ? p : (PP - 1);
        int py = pcl / HF, px = pcl - py * HF;
        const float* base = img + py * IW + px;
        unsigned us[8];
        #pragma unroll
        for (int e = 0; e < 8; ++e) {
            int ch = kg * 8 + e;
            float v;
            if (ch < C75) {
                int c = ch / 25, rem = ch - c * 25, ky = rem / 5, kx = rem - ky * 5;
                v = base[(c * IW + ky) * IW + kx];
            } else if (ch == 75) v = SQ01 * (float)py * (1.f / 62.f);
            else if (ch == 76)   v = SQ01 * (float)px * (1.f / 62.f);
            else v = 0.f;
            __hip_bfloat16 h = __float2bfloat16(v);
            us[e] = *reinterpret_cast<unsigned short*>(&h);
        }
        int4 o;
        o.x = (int)(us[0] | (us[1] << 16));
        o.y = (int)(us[2] | (us[3] << 16));
        o.z = (int)(us[4] | (us[5] << 16));
        o.w = (int)(us[6] | (us[7] << 16));
        fb[idx] = o;
    } else {
        int idx = (b - FEAT_BLOCKS) * 256 + tid;
        if (idx == 0) atomicExch(cnt, 0u);      // reset arrive-counter each call
        int p = idx & (PPAD - 1);
        int nq = idx >> 12; int n = nq & (NB - 1); int which = nq >> 2;
        float* dst = (which ? QjA : PiA) + n * PPAD + p;
        if (p >= PP) { *dst = which ? 1e30f : 0.f; return; }
        if (!which) dminU[n * PP + p] = 0x7f800000u;
        int py = p / HF, px = p - py * HF;
        float cy = (float)py * (1.f / 62.f), cx = (float)px * (1.f / 62.f);
        float s = WSP * (cy * cy + cx * cx);
        const float* img = (which ? tgtI : outI) + n * IMGSZ + py * IW + px;
        #pragma unroll
        for (int c = 0; c < 3; ++c)
            #pragma unroll
            for (int ky = 0; ky < 5; ++ky)
                #pragma unroll
                for (int kx = 0; kx < 5; ++kx) {
                    float v = img[(c * IW + ky) * IW + kx];
                    s = fmaf(v, v, s);
                }
        *dst = s;
    }
}

// ---------------- main pass: BM=256, 512 thr, XCD-aware block swizzle -----
// Linear 256-block grid; bid%8 = XCD (HW round-robin). XCD x owns combos
// {2x, 2x+1} (combo = n*4+sl), 16 i-tiles each -> per-XCD L2 working set
// = full A of one image (786KB) + 2 B-slices (394KB) ~ 1.2MB << 4MB L2.
// Without this, each XCD touched all 16 B-slices (~4.7MB) and the per-chunk
// vmcnt(0) drain waited on L3.
template<int PASS>
__global__ __launch_bounds__(512, 2) void k_pass(const int4* __restrict__ fb,
                                                 const float* __restrict__ PiA,
                                                 const float* __restrict__ QjA,
                                                 unsigned* __restrict__ dminU,
                                                 float* __restrict__ part) {
    __shared__ __align__(16) int4 lB[2][NKG * BN];
    __shared__ float red[2 * BM];

    const int tid = threadIdx.x;
    const int bid = blockIdx.x;
    const int xcd = bid & 7, k = bid >> 3;
    const int combo = xcd * 2 + (k >> 4);     // 0..15, 16 blocks each
    const int it = k & 15;
    const int n = combo >> 2, sl = combo & 3;
    const int i0 = it * BM;
    const int wid = tid >> 6, lane = tid & 63;
    const int wr = wid >> 1, wc = wid & 1;          // wr 0..3, wc 0..1
    const int g = lane >> 4, c16 = lane & 15;

    const int4* fbA = fb + (size_t)(n * NKG) * PPAD;
    const int4* fbB = fb + (size_t)((NB + n) * NKG) * PPAD;

    // A fragments global -> registers, once (wave covers rows wr*64..wr*64+63)
    short8 af[3][4];
    #pragma unroll
    for (int ks = 0; ks < 3; ++ks)
        #pragma unroll
        for (int mf = 0; mf < 4; ++mf)
            af[ks][mf] = *reinterpret_cast<const short8*>(
                &fbA[(ks * 4 + g) * PPAD + i0 + wr * 64 + mf * 16 + c16]);

    float rmin[16], racc[16], slope[16], c0[16];
    #pragma unroll
    for (int mf = 0; mf < 4; ++mf)
        #pragma unroll
        for (int r = 0; r < 4; ++r) {
            int q = mf * 4 + r;
            rmin[q] = 1e30f; racc[q] = 0.f;
            if (PASS == 2) {
                int i = i0 + wr * 64 + mf * 16 + g * 4 + r;
                int ic = (i < PP) ? i : (PP - 1);
                float u = LOG2E2 / (__uint_as_float(dminU[n * PP + ic]) + EPSV);
                slope[q] = 2.f * u;
                c0[q] = fmaf(-u, PiA[n * PPAD + i], LOG2E2);
            }
        }

    // async stage chunk 0 into buf 0 (3 x 16B per wave, linear LDS dest)
    const int seg0 = wid * 3;
    {
        const int j0 = (sl * CH_PER_SL) * BN;
        #pragma unroll
        for (int s2 = 0; s2 < 3; ++s2) {
            int idx = (seg0 + s2) * 64 + lane;
            int kg = idx >> 7, col = idx & 127;
            gload_lds16(&fbB[kg * PPAD + j0 + col], &lB[0][(seg0 + s2) * 64]);
        }
    }
    __syncthreads();

    int cur = 0;
    for (int ch = 0; ch < CH_PER_SL; ++ch) {
        const int j0 = (sl * CH_PER_SL + ch) * BN;
        if (ch + 1 < CH_PER_SL) {
            const int j1 = j0 + BN;
            #pragma unroll
            for (int s2 = 0; s2 < 3; ++s2) {
                int idx = (seg0 + s2) * 64 + lane;
                int kg = idx >> 7, col = idx & 127;
                gload_lds16(&fbB[kg * PPAD + j1 + col], &lB[cur ^ 1][(seg0 + s2) * 64]);
            }
        }
        float qj[4];
        #pragma unroll
        for (int nf = 0; nf < 4; ++nf)
            qj[nf] = QjA[n * PPAD + j0 + wc * 64 + nf * 16 + c16];

        f32x4 acc[4][4];
        #pragma unroll
        for (int mf = 0; mf < 4; ++mf)
            #pragma unroll
            for (int nf = 0; nf < 4; ++nf)
                acc[mf][nf] = (f32x4)(0.f);

        #pragma unroll
        for (int ks = 0; ks < 3; ++ks) {
            short8 bfr[4];
            #pragma unroll
            for (int nf = 0; nf < 4; ++nf)
                bfr[nf] = *reinterpret_cast<const short8*>(
                    &lB[cur][(ks * 4 + g) * BN + wc * 64 + nf * 16 + c16]);
            #pragma unroll
            for (int mf = 0; mf < 4; ++mf)
                #pragma unroll
                for (int nf = 0; nf < 4; ++nf)
                    acc[mf][nf] = __builtin_amdgcn_mfma_f32_16x16x32_bf16(af[ks][mf], bfr[nf], acc[mf][nf], 0, 0, 0);
        }

        if (PASS == 1) {
            #pragma unroll
            for (int nf = 0; nf < 4; ++nf)
                #pragma unroll
                for (int mf = 0; mf < 4; ++mf)
                    #pragma unroll
                    for (int r = 0; r < 4; ++r) {
                        int q = mf * 4 + r;
                        rmin[q] = fminf(rmin[q], fmaf(-2.f, acc[mf][nf][r], qj[nf]));
                    }
        } else {
            #pragma unroll
            for (int nf = 0; nf < 4; ++nf) {
                float qjh = -0.5f * qj[nf];
                float bq[16];
                #pragma unroll
                for (int q = 0; q < 16; ++q)
                    bq[q] = fmaf(slope[q], qjh, c0[q]);
                #pragma unroll
                for (int mf = 0; mf < 4; ++mf)
                    #pragma unroll
                    for (int r = 0; r < 4; ++r) {
                        int q = mf * 4 + r;
                        racc[q] += __builtin_amdgcn_exp2f(fmaf(slope[q], acc[mf][nf][r], bq[q]));
                    }
            }
        }
        __syncthreads();
        cur ^= 1;
    }

    #pragma unroll
    for (int q = 0; q < 16; ++q) {
        float v = (PASS == 1) ? rmin[q] : racc[q];
        #pragma unroll
        for (int m = 1; m <= 8; m <<= 1) {
            float o = __shfl_xor(v, m);
            v = (PASS == 1) ? fminf(v, o) : (v + o);
        }
        if (c16 == 0) {
            int mf = q >> 2, r = q & 3;
            red[wc * BM + wr * 64 + mf * 16 + g * 4 + r] = v;
        }
    }
    __syncthreads();
    if (tid < BM) {
        int i = i0 + tid;
        if (i < PP) {
            if (PASS == 1) {
                float v = fminf(red[tid], red[BM + tid]) + PiA[n * PPAD + i];
                atomicMin(dminU + n * PP + i, __float_as_uint(v));
            } else {
                part[(n * NSLICE + sl) * PP + i] = red[tid] + red[BM + tid];
            }
        }
    }
}

// ---------------- fused finish: 64 blocks + last-block final reduce -------
__global__ __launch_bounds__(256) void k_fin(const unsigned* __restrict__ dminU,
                                             const float* __restrict__ part,
                                             float* __restrict__ fpart,
                                             unsigned* __restrict__ cnt,
                                             float* __restrict__ out) {
    __shared__ float red[256];
    __shared__ int lastFlag;
    int b = blockIdx.x;           // 64
    int n = b >> 4, c = b & 15;
    int tid = threadIdx.x;
    int i = c * 256 + tid;
    float v = 0.f;
    if (i < PP) {
        float dm = __uint_as_float(dminU[n * PP + i]);
        float inv = 1.f / (dm + EPSV);
        float num = __expf(2.f * (1.f - dm * inv));
        float S = part[(n * NSLICE + 0) * PP + i] + part[(n * NSLICE + 1) * PP + i]
                + part[(n * NSLICE + 2) * PP + i] + part[(n * NSLICE + 3) * PP + i];
        v = num / S;
    }
    red[tid] = v; __syncthreads();
    for (int w = 128; w > 0; w >>= 1) { if (tid < w) red[tid] += red[tid + w]; __syncthreads(); }
    if (tid == 0) {
        atomicExch(&fpart[b], red[0]);
        __threadfence();
        unsigned old = atomicAdd(cnt, 1u);
        lastFlag = (old == 63u);
    }
    __syncthreads();
    if (lastFlag && tid < 64) {
        __threadfence();
        float s = atomicAdd(&fpart[tid], 0.f);   // coherent read of partial
        s += __shfl_xor(s, 1);
        s += __shfl_xor(s, 2);
        s += __shfl_xor(s, 4);
        s += __shfl_xor(s, 8);
        float s0 = __shfl(s, 0);
        float s1 = __shfl(s, 16);
        float s2 = __shfl(s, 32);
        float s3 = __shfl(s, 48);
        if (tid == 0) {
            const float invP = 1.f / (float)PP;
            out[0] = -(__logf(s0 * invP) + __logf(s1 * invP)
                     + __logf(s2 * invP) + __logf(s3 * invP));
        }
    }
}

// ---------------- fallback f32 path (round-1, verified; centered) ---------
__global__ void k_init(unsigned* __restrict__ dminU) {
    int g = blockIdx.x * 256 + threadIdx.x;
    if (g < NB * PP) dminU[g] = 0x7f800000u;
}

__global__ __launch_bounds__(256) void k_mean(const float* __restrict__ tgt,
                                              float* __restrict__ meanv) {
    __shared__ float red[256];
    int c75 = blockIdx.x;
    int c = c75 / 25, rem = c75 - c * 25, ky = rem / 5, kx = rem - ky * 5;
    int tid = threadIdx.x;
    float s = 0.f;
    for (int idx = tid; idx < NB * PP; idx += 256) {
        int n = idx / PP, p = idx - n * PP;
        int py = p / HF, px = p - py * HF;
        s += tgt[n * IMGSZ + (c * IW + py + ky) * IW + px + kx];
    }
    red[tid] = s; __syncthreads();
    for (int w = 128; w > 0; w >>= 1) { if (tid < w) red[tid] += red[tid + w]; __syncthreads(); }
    if (tid == 0) meanv[c75] = red[0] * (1.f / (float)(NB * PP));
}

__global__ __launch_bounds__(256) void k_rsqF(const float* __restrict__ outI,
                                              const float* __restrict__ tgtI,
                                              const float* __restrict__ meanv,
                                              float* __restrict__ rI, float* __restrict__ rT) {
    int gidx = blockIdx.x * 256 + threadIdx.x;
    if (gidx >= 2 * NB * PP) return;
    int which = gidx / (NB * PP); int rem = gidx - which * NB * PP;
    int n = rem / PP, p = rem - n * PP;
    int py = p / HF, px = p - py * HF;
    const float* img = (which ? tgtI : outI) + n * IMGSZ;
    float s = 0.f;
    #pragma unroll
    for (int c = 0; c < 3; ++c)
        #pragma unroll
        for (int ky = 0; ky < 5; ++ky)
            #pragma unroll
            for (int kx = 0; kx < 5; ++kx) {
                float v = img[(c * IW + py + ky) * IW + px + kx] - meanv[(c * 5 + ky) * 5 + kx];
                s = fmaf(v, v, s);
            }
    (which ? rT : rI)[n * PP + p] = s;
}

__device__ __forceinline__ void stage_featF(const float* __restrict__ img,
                                            const float* __restrict__ meanv,
                                            float* __restrict__ lds, int p0, int tid) {
    for (int idx = tid; idx < C75 * 128; idx += 256) {
        int c75 = idx >> 7, col = idx & 127;
        int p = p0 + col; p = (p < PP) ? p : (PP - 1);
        int py = p / HF, px = p - py * HF;
        int c = c75 / 25, rem = c75 - c * 25, ky = rem / 5, kx = rem - ky * 5;
        lds[idx] = img[(c * IW + py + ky) * IW + px + kx] - meanv[c75];
    }
}

template<int PASS>
__global__ __launch_bounds__(256, 2) void k_passF(const float* __restrict__ outI,
                                                  const float* __restrict__ tgtI,
                                                  const float* __restrict__ meanv,
                                                  const float* __restrict__ rI,
                                                  const float* __restrict__ rT,
                                                  unsigned* __restrict__ dminU,
                                                  float* __restrict__ part) {
    __shared__ __align__(16) float lA[C75 * 128];
    __shared__ __align__(16) float lB[C75 * 128];
    __shared__ float red[4 * 128];
    __shared__ float lrT[128];

    const int tid = threadIdx.x;
    const int it = blockIdx.x, sl = blockIdx.y, n = blockIdx.z;
    const int i0 = it * 128;
    const int ti4 = (tid & 15) * 4;
    const int tj4 = (tid >> 4) * 4;

    stage_featF(outI + n * IMGSZ, meanv, lA, i0, tid);

    int lr[8]; float iyn[8], ixn[8], rIr[8], invr[8];
    #pragma unroll
    for (int r = 0; r < 8; ++r) {
        lr[r] = (r < 4) ? (ti4 + r) : (64 + ti4 + (r - 4));
        int i = i0 + lr[r]; int ic = (i < PP) ? i : (PP - 1);
        int iy = ic / HF, ix = ic - iy * HF;
        iyn[r] = (float)iy / 62.f; ixn[r] = (float)ix / 62.f;
        rIr[r] = rI[n * PP + ic];
        if (PASS == 2) {
            float dm = __uint_as_float(dminU[n * PP + ic]);
            invr[r] = 1.f / (dm + EPSV);
        }
    }

    float raccF[8];
    #pragma unroll
    for (int r = 0; r < 8; ++r) raccF[r] = (PASS == 1) ? 3.0e38f : 0.f;

    for (int ch = 0; ch < CH_PER_SL; ++ch) {
        const int j0 = (sl * CH_PER_SL + ch) * 128;
        __syncthreads();
        stage_featF(tgtI + n * IMGSZ, meanv, lB, j0, tid);
        if (tid < 128) {
            int j = j0 + tid;
            lrT[tid] = rT[n * PP + ((j < PP) ? j : (PP - 1))];
        }
        __syncthreads();

        float jyn[8], jxn[8], rTr[8]; bool jok[8];
        #pragma unroll
        for (int s = 0; s < 8; ++s) {
            int jc = (s < 4) ? (tj4 + s) : (64 + tj4 + (s - 4));
            int j = j0 + jc;
            jok[s] = (j < PP);
            int jcl = jok[s] ? j : (PP - 1);
            int jy = jcl / HF, jx = jcl - jy * HF;
            jyn[s] = (float)jy / 62.f; jxn[s] = (float)jx / 62.f;
            rTr[s] = lrT[jc];
        }

        float acc[8][8];
        #pragma unroll
        for (int r = 0; r < 8; ++r)
            #pragma unroll
            for (int s = 0; s < 8; ++s) acc[r][s] = 0.f;

        #pragma unroll 3
        for (int c = 0; c < C75; ++c) {
            const float4 a0 = *reinterpret_cast<const float4*>(lA + c * 128 + ti4);
            const float4 a1 = *reinterpret_cast<const float4*>(lA + c * 128 + 64 + ti4);
            const float4 b0 = *reinterpret_cast<const float4*>(lB + c * 128 + tj4);
            const float4 b1 = *reinterpret_cast<const float4*>(lB + c * 128 + 64 + tj4);
            const float av[8] = {a0.x, a0.y, a0.z, a0.w, a1.x, a1.y, a1.z, a1.w};
            const float bv[8] = {b0.x, b0.y, b0.z, b0.w, b1.x, b1.y, b1.z, b1.w};
            #pragma unroll
            for (int r = 0; r < 8; ++r)
                #pragma unroll
                for (int s = 0; s < 8; ++s)
                    acc[r][s] = fmaf(av[r], bv[s], acc[r][s]);
        }

        #pragma unroll
        for (int r = 0; r < 8; ++r) {
            #pragma unroll
            for (int s = 0; s < 8; ++s) {
                float d = rIr[r] + rTr[s] - 2.f * acc[r][s];
                d = fmaxf(d, 0.f);
                float dy = iyn[r] - jyn[s], dx = ixn[r] - jxn[s];
                float comb = d + WSP * (dy * dy + dx * dx);
                if (PASS == 1) {
                    raccF[r] = fminf(raccF[r], jok[s] ? comb : 3.0e38f);
                } else {
                    float w = __expf(2.f * (1.f - comb * invr[r]));
                    raccF[r] += jok[s] ? w : 0.f;
                }
            }
        }
    }

    const int wv = tid >> 6;
    const bool wrt = ((tid >> 4) & 3) == 0;
    #pragma unroll
    for (int r = 0; r < 8; ++r) {
        float v = raccF[r];
        if (PASS == 1) {
            v = fminf(v, __shfl_xor(v, 16));
            v = fminf(v, __shfl_xor(v, 32));
        } else {
            v += __shfl_xor(v, 16);
            v += __shfl_xor(v, 32);
        }
        if (wrt) red[wv * 128 + lr[r]] = v;
    }
    __syncthreads();
    if (tid < 128) {
        int i = i0 + tid;
        if (i < PP) {
            if (PASS == 1) {
                float v = fminf(fminf(red[tid], red[128 + tid]),
                                fminf(red[256 + tid], red[384 + tid]));
                atomicMin(dminU + n * PP + i, __float_as_uint(v));
            } else {
                float v = red[tid] + red[128 + tid] + red[256 + tid] + red[384 + tid];
                part[(n * NSLICE + sl) * PP + i] = v;
            }
        }
    }
}

__global__ __launch_bounds__(256) void k_finF(const unsigned* __restrict__ dminU,
                                              const float* __restrict__ part,
                                              float* __restrict__ out) {
    __shared__ float red[256];
    int tid = threadIdx.x;
    float loss = 0.f;
    for (int n = 0; n < NB; ++n) {
        float local = 0.f;
        for (int i = tid; i < PP; i += 256) {
            float dm = __uint_as_float(dminU[n * PP + i]);
            float inv = 1.f / (dm + EPSV);
            float num = __expf(2.f * (1.f - dm * inv));
            float S = part[(n * NSLICE + 0) * PP + i] + part[(n * NSLICE + 1) * PP + i]
                    + part[(n * NSLICE + 2) * PP + i] + part[(n * NSLICE + 3) * PP + i];
            local += num / S;
        }
        red[tid] = local; __syncthreads();
        for (int w = 128; w > 0; w >>= 1) { if (tid < w) red[tid] += red[tid + w]; __syncthreads(); }
        if (tid == 0) loss -= __logf(red[0] * (1.f / (float)PP));
        __syncthreads();
    }
    if (tid == 0) out[0] = loss;
}

// ---------------- launcher ----------------
extern "C" void kernel_launch(void* const* d_in, const int* in_sizes, int n_in,
                              void* d_out, int out_size, void* d_ws, size_t ws_size,
                              hipStream_t stream) {
    const float* outI = (const float*)d_in[0];
    const float* tgtI = (const float*)d_in[1];
    float* ws = (float*)d_ws;
    float* outp = (float*)d_out;

    if (ws_size >= NEED_BYTES) {
        float* PiA = ws + OFF_PI;
        float* QjA = ws + OFF_QJ;
        unsigned* dminU = (unsigned*)(ws + OFF_DMIN);
        float* part = ws + OFF_PART;
        float* fpart = ws + OFF_FPART;
        unsigned* cnt = (unsigned*)(ws + OFF_CNT);
        int4* fb = (int4*)(ws + OFF_FB);

        k_featpq<<<FEAT_BLOCKS + PQ_BLOCKS, 256, 0, stream>>>(outI, tgtI, fb, PiA, QjA, dminU, cnt);
        k_pass<1><<<256, 512, 0, stream>>>(fb, PiA, QjA, dminU, part);
        k_pass<2><<<256, 512, 0, stream>>>(fb, PiA, QjA, dminU, part);
        k_fin<<<64, 256, 0, stream>>>(dminU, part, fpart, cnt, outp);
    } else {
        float* meanv = ws + OLD_MEAN;
        float* rI = ws + OLD_RI;
        float* rT = ws + OLD_RT;
        unsigned* dminU = (unsigned*)(ws + OLD_DMIN);
        float* part = ws + OLD_PART;

        k_init<<<(NB * PP + 255) / 256, 256, 0, stream>>>(dminU);
        k_mean<<<C75, 256, 0, stream>>>(tgtI, meanv);
        k_rsqF<<<(2 * NB * PP + 255) / 256, 256, 0, stream>>>(outI, tgtI, meanv, rI, rT);
        dim3 g(32, NSLICE, NB);
        k_passF<1><<<g, 256, 0, stream>>>(outI, tgtI, meanv, rI, rT, dminU, part);
        k_passF<2><<<g, 256, 0, stream>>>(outI, tgtI, meanv, rI, rT, dminU, part);
        k_finF<<<1, 256, 0, stream>>>(dminU, part, outp);
    }
}